// Round 13
// baseline (55.627 us; speedup 1.0000x reference)
//
#include <hip/hip_runtime.h>
#include <hip/hip_fp16.h>
#include <math.h>

#define NB 8          // NUM_BINS
#define DD 32         // D
constexpr float TB   = 10.0f;   // TAIL_BOUND
constexpr float MBW  = 1e-3f;   // MIN_BIN_WIDTH
constexpr float MBH  = 1e-3f;   // MIN_BIN_HEIGHT
constexpr float MDER = 1e-3f;   // MIN_DERIVATIVE

typedef float f32x4 __attribute__((ext_vector_type(4)));

__device__ __forceinline__ float softplusf(float v) {
    return (v > 20.0f) ? v : log1pf(expf(v));
}

__global__ __launch_bounds__(256, 4) void mfb_kernel(
    const float* __restrict__ x,
    const float* __restrict__ uw,
    const float* __restrict__ uh,
    const float* __restrict__ ud,
    float* __restrict__ out,
    int n4)
{
    // Round-12 math/data structure exactly. Single variable: partition shape.
    // R12 (4KB bursts, 32MB apart per wave) confirmed the DRAM-stream-shape
    // lever (58->52.5us). This round: BLOCKED ownership — each wave owns one
    // contiguous 16KB chunk (1024 quads), streamed as 4 x (4KB burst). Every
    // wave's read AND write streams are now purely sequential. Dim invariant
    // unchanged: all offsets are 0 mod 32 except 4*lane -> dbase = 4*(l&7).
    __shared__ float4 s_T[DD][NB + 1];
    __shared__ float  s_kn[DD][7];

    const int t = threadIdx.x;

    if (t < DD) {
        float posw[NB + 1], posh[NB + 1], dv[NB + 1];
        // ---- widths ----
        {
            float u[NB];
            float m = -1e30f;
            #pragma unroll
            for (int k = 0; k < NB; ++k) { u[k] = uw[t * NB + k]; m = fmaxf(m, u[k]); }
            float s = 0.0f;
            #pragma unroll
            for (int k = 0; k < NB; ++k) { u[k] = expf(u[k] - m); s += u[k]; }
            const float inv = 1.0f / s;
            posw[0] = -TB;
            float cum = 0.0f;
            #pragma unroll
            for (int k = 0; k < NB; ++k) {
                cum += MBW + (1.0f - MBW * (float)NB) * (u[k] * inv);
                posw[k + 1] = 2.0f * TB * cum - TB;
            }
            posw[NB] = TB;
        }
        // ---- heights ----
        {
            float u[NB];
            float m = -1e30f;
            #pragma unroll
            for (int k = 0; k < NB; ++k) { u[k] = uh[t * NB + k]; m = fmaxf(m, u[k]); }
            float s = 0.0f;
            #pragma unroll
            for (int k = 0; k < NB; ++k) { u[k] = expf(u[k] - m); s += u[k]; }
            const float inv = 1.0f / s;
            posh[0] = -TB;
            float cum = 0.0f;
            #pragma unroll
            for (int k = 0; k < NB; ++k) {
                cum += MBH + (1.0f - MBH * (float)NB) * (u[k] * inv);
                posh[k + 1] = 2.0f * TB * cum - TB;
            }
            posh[NB] = TB;
        }
        // ---- derivatives ----
        {
            const float c   = logf(expm1f(1.0f - MDER));
            const float bnd = MDER + softplusf(c);   // == 1.0 to fp precision
            dv[0]  = bnd;
            dv[NB] = bnd;
            #pragma unroll
            for (int k = 1; k < NB; ++k)
                dv[k] = MDER + softplusf(ud[t * (NB - 1) + (k - 1)]);
        }
        // ---- publish ----
        #pragma unroll
        for (int k = 0; k < 7; ++k) s_kn[t][k] = posw[k + 1];
        const int key = (t >> 2) & 7;
        #pragma unroll
        for (int b = 0; b < NB; ++b) {
            const float w    = posw[b + 1] - posw[b];
            const float invw = 1.0f / w;
            const unsigned u1 = ((unsigned)__half_as_ushort(__float2half_rn(posh[b + 1] - posh[b])) << 16)
                              |  (unsigned)__half_as_ushort(__float2half_rn(posh[b]));
            const unsigned u2 = ((unsigned)__half_as_ushort(__float2half_rn(dv[b + 1])) << 16)
                              |  (unsigned)__half_as_ushort(__float2half_rn(dv[b]));
            float4 T;
            T.x = invw;
            T.y = -posw[b] * invw;
            T.z = __uint_as_float(u1);
            T.w = __uint_as_float(u2);
            s_T[t][b ^ key] = T;
        }
    }
    __syncthreads();

    constexpr float HALF_LOG_2PI = 0.91893853320467274178f;
    constexpr float LN2          = 0.69314718055994530942f;

    const int g      = blockIdx.x * blockDim.x + t;
    const int nT     = gridDim.x * blockDim.x;
    const int l      = g & 63;                 // lane
    // blocked & grid-stride paths both give dim quad = 4*(l&7) (offsets 0 mod 32)
    const int dbase  = (l * 4) & (DD - 1);
    const int key    = (dbase >> 2) & 7;

    float a0 = s_kn[dbase + 0][0], a1 = s_kn[dbase + 0][1], a2 = s_kn[dbase + 0][2],
          a3 = s_kn[dbase + 0][3], a4 = s_kn[dbase + 0][4], a5 = s_kn[dbase + 0][5],
          a6 = s_kn[dbase + 0][6];
    float b0 = s_kn[dbase + 1][0], b1 = s_kn[dbase + 1][1], b2 = s_kn[dbase + 1][2],
          b3 = s_kn[dbase + 1][3], b4 = s_kn[dbase + 1][4], b5 = s_kn[dbase + 1][5],
          b6 = s_kn[dbase + 1][6];
    float c0 = s_kn[dbase + 2][0], c1 = s_kn[dbase + 2][1], c2 = s_kn[dbase + 2][2],
          c3 = s_kn[dbase + 2][3], c4 = s_kn[dbase + 2][4], c5 = s_kn[dbase + 2][5],
          c6 = s_kn[dbase + 2][6];
    float e0 = s_kn[dbase + 3][0], e1 = s_kn[dbase + 3][1], e2 = s_kn[dbase + 3][2],
          e3 = s_kn[dbase + 3][3], e4 = s_kn[dbase + 3][4], e5 = s_kn[dbase + 3][5],
          e6 = s_kn[dbase + 3][6];

    const float4* __restrict__ r0 = &s_T[dbase + 0][0];
    const float4* __restrict__ r1 = &s_T[dbase + 1][0];
    const float4* __restrict__ r2 = &s_T[dbase + 2][0];
    const float4* __restrict__ r3 = &s_T[dbase + 3][0];

    auto evalone = [&](float xx,
                       float k0, float k1, float k2, float k3, float k4, float k5, float k6,
                       const float4* __restrict__ row) -> float {
        // 3-level binary search (round 11)
        const bool  gt3 = xx >= k3;
        const float kA  = gt3 ? k5 : k1;
        const bool  gtA = xx >= kA;
        const float kB0 = gt3 ? k4 : k0;
        const float kB1 = gt3 ? k6 : k2;
        const float kB  = gtA ? kB1 : kB0;
        const bool  gtB = xx >= kB;
        int idx = (gtB ? 1 : 0) + (gtA ? 2 : 0) + (gt3 ? 4 : 0);

        const float4 T = row[idx ^ key];   // one ds_read_b128

        const __half2* hp = reinterpret_cast<const __half2*>(&T.z);
        const float2 f1 = __half22float2(hp[0]);   // {ch, h}
        const float2 f2 = __half22float2(hp[1]);   // {d0, d1}
        const float ch = f1.x, h = f1.y, d0 = f2.x, d1 = f2.y;

        const float theta = fmaf(xx, T.x, T.y);
        const float delta = h * T.x;                              // h*invw
        const float dmd   = delta - d0;
        const float s2    = fmaf(-2.0f, delta, d0 + d1);
        const float u     = fmaf(-theta, theta, theta);           // θ(1-θ)
        const float den   = fmaf(s2, u, delta);
        const float rden  = __builtin_amdgcn_rcpf(den);
        const float num1  = (h * theta) * fmaf(theta, dmd, d0);   // hθ(θ(δ-d0)+d0)
        const float zin   = fmaf(num1, rden, ch);
        const float poly  = fmaf(fmaf(s2, theta, dmd + dmd), theta, d0);
        const float ee    = delta * rden;
        const float lg2   = __log2f(poly * (ee * ee));

        const bool inside = fabsf(xx) <= TB;
        const float z    = inside ? zin : xx;
        const float lg2s = inside ? lg2 : 0.0f;
        return fmaf(z * z, -0.5f, fmaf(lg2s, LN2, -HALF_LOG_2PI));
    };

    auto eval4 = [&](f32x4 xv) -> f32x4 {
        f32x4 r;
        r.x = evalone(xv.x, a0, a1, a2, a3, a4, a5, a6, r0);
        r.y = evalone(xv.y, b0, b1, b2, b3, b4, b5, b6, r1);
        r.z = evalone(xv.z, c0, c1, c2, c3, c4, c5, c6, r2);
        r.w = evalone(xv.w, e0, e1, e2, e3, e4, e5, e6, r3);
        return r;
    };

    const f32x4* __restrict__ x4 = reinterpret_cast<const f32x4*>(x);
    f32x4* __restrict__ o4 = reinterpret_cast<f32x4*>(out);

    const int W  = g >> 6;            // global wave id
    const int nW = nT >> 6;           // total waves
    const int chunk = n4 / nW;        // quads per wave (1024 at this shape)

    if (chunk * nW == n4 && (chunk & 255) == 0) {
        // ---- blocked-contiguous main loop: wave W owns quads
        //      [W*chunk, (W+1)*chunk), streamed as 4KB bursts ----
        const int base0 = W * chunk + l;
        for (int c = 0; c < chunk; c += 256) {
            const int base = base0 + c;
            const f32x4 v0 = x4[base];
            const f32x4 v1 = x4[base + 64];
            const f32x4 v2 = x4[base + 128];
            const f32x4 v3 = x4[base + 192];
            __builtin_nontemporal_store(eval4(v0), &o4[base]);
            __builtin_nontemporal_store(eval4(v1), &o4[base + 64]);
            __builtin_nontemporal_store(eval4(v2), &o4[base + 128]);
            __builtin_nontemporal_store(eval4(v3), &o4[base + 192]);
        }
    } else {
        // general fallback (not hit at N=1048576, D=32)
        for (int i = g; i < n4; i += nT) {
            const f32x4 xa = x4[i];
            __builtin_nontemporal_store(eval4(xa), &o4[i]);
        }
    }
}

extern "C" void kernel_launch(void* const* d_in, const int* in_sizes, int n_in,
                              void* d_out, int out_size, void* d_ws, size_t ws_size,
                              hipStream_t stream) {
    const float* x  = (const float*)d_in[0];
    const float* uw = (const float*)d_in[1];
    const float* uh = (const float*)d_in[2];
    const float* ud = (const float*)d_in[3];
    float* out = (float*)d_out;

    const int n4 = in_sizes[0] / 4;                 // N*D/4 float4 elements
    int blocks = (n4 + 255) / 256;
    if (blocks > 2048) blocks = 2048;

    mfb_kernel<<<blocks, 256, 0, stream>>>(x, uw, uh, ud, out, n4);
}

// Round 14
// 53.692 us; speedup vs baseline: 1.0360x; 1.0360x over previous
//
#include <hip/hip_runtime.h>
#include <hip/hip_fp16.h>
#include <math.h>

#define NB 8          // NUM_BINS
#define DD 32         // D
constexpr float TB   = 10.0f;   // TAIL_BOUND
constexpr float MBW  = 1e-3f;   // MIN_BIN_WIDTH
constexpr float MBH  = 1e-3f;   // MIN_BIN_HEIGHT
constexpr float MDER = 1e-3f;   // MIN_DERIVATIVE

typedef float f32x4 __attribute__((ext_vector_type(4)));

__device__ __forceinline__ float softplusf(float v) {
    return (v > 20.0f) ? v : log1pf(expf(v));
}

__global__ __launch_bounds__(256, 4) void mfb_kernel(
    const float* __restrict__ x,
    const float* __restrict__ uw,
    const float* __restrict__ uh,
    const float* __restrict__ ud,
    float* __restrict__ out,
    int n4)
{
    // Round-12 structure exactly (best: 52.5us — 4KB bursts, coherent 32MB
    // global sweep; R13's blocked variant regressed). Single variable this
    // round: burst-level software pipeline — issue super-iteration s+1's four
    // loads BEFORE computing/storing s, so loads are in flight during the
    // whole compute+store block instead of only between bursts.
    __shared__ float4 s_T[DD][NB + 1];
    __shared__ float  s_kn[DD][7];

    const int t = threadIdx.x;

    if (t < DD) {
        float posw[NB + 1], posh[NB + 1], dv[NB + 1];
        // ---- widths ----
        {
            float u[NB];
            float m = -1e30f;
            #pragma unroll
            for (int k = 0; k < NB; ++k) { u[k] = uw[t * NB + k]; m = fmaxf(m, u[k]); }
            float s = 0.0f;
            #pragma unroll
            for (int k = 0; k < NB; ++k) { u[k] = expf(u[k] - m); s += u[k]; }
            const float inv = 1.0f / s;
            posw[0] = -TB;
            float cum = 0.0f;
            #pragma unroll
            for (int k = 0; k < NB; ++k) {
                cum += MBW + (1.0f - MBW * (float)NB) * (u[k] * inv);
                posw[k + 1] = 2.0f * TB * cum - TB;
            }
            posw[NB] = TB;
        }
        // ---- heights ----
        {
            float u[NB];
            float m = -1e30f;
            #pragma unroll
            for (int k = 0; k < NB; ++k) { u[k] = uh[t * NB + k]; m = fmaxf(m, u[k]); }
            float s = 0.0f;
            #pragma unroll
            for (int k = 0; k < NB; ++k) { u[k] = expf(u[k] - m); s += u[k]; }
            const float inv = 1.0f / s;
            posh[0] = -TB;
            float cum = 0.0f;
            #pragma unroll
            for (int k = 0; k < NB; ++k) {
                cum += MBH + (1.0f - MBH * (float)NB) * (u[k] * inv);
                posh[k + 1] = 2.0f * TB * cum - TB;
            }
            posh[NB] = TB;
        }
        // ---- derivatives ----
        {
            const float c   = logf(expm1f(1.0f - MDER));
            const float bnd = MDER + softplusf(c);   // == 1.0 to fp precision
            dv[0]  = bnd;
            dv[NB] = bnd;
            #pragma unroll
            for (int k = 1; k < NB; ++k)
                dv[k] = MDER + softplusf(ud[t * (NB - 1) + (k - 1)]);
        }
        // ---- publish ----
        #pragma unroll
        for (int k = 0; k < 7; ++k) s_kn[t][k] = posw[k + 1];
        const int key = (t >> 2) & 7;
        #pragma unroll
        for (int b = 0; b < NB; ++b) {
            const float w    = posw[b + 1] - posw[b];
            const float invw = 1.0f / w;
            const unsigned u1 = ((unsigned)__half_as_ushort(__float2half_rn(posh[b + 1] - posh[b])) << 16)
                              |  (unsigned)__half_as_ushort(__float2half_rn(posh[b]));
            const unsigned u2 = ((unsigned)__half_as_ushort(__float2half_rn(dv[b + 1])) << 16)
                              |  (unsigned)__half_as_ushort(__float2half_rn(dv[b]));
            float4 T;
            T.x = invw;
            T.y = -posw[b] * invw;
            T.z = __uint_as_float(u1);
            T.w = __uint_as_float(u2);
            s_T[t][b ^ key] = T;
        }
    }
    __syncthreads();

    constexpr float HALF_LOG_2PI = 0.91893853320467274178f;
    constexpr float LN2          = 0.69314718055994530942f;

    const int g      = blockIdx.x * blockDim.x + t;
    const int nT     = gridDim.x * blockDim.x;
    const int l      = g & 63;                 // lane
    // burst & grid-stride paths both give dim quad = 4*(l&7) (offsets 0 mod 32)
    const int dbase  = (l * 4) & (DD - 1);
    const int key    = (dbase >> 2) & 7;

    float a0 = s_kn[dbase + 0][0], a1 = s_kn[dbase + 0][1], a2 = s_kn[dbase + 0][2],
          a3 = s_kn[dbase + 0][3], a4 = s_kn[dbase + 0][4], a5 = s_kn[dbase + 0][5],
          a6 = s_kn[dbase + 0][6];
    float b0 = s_kn[dbase + 1][0], b1 = s_kn[dbase + 1][1], b2 = s_kn[dbase + 1][2],
          b3 = s_kn[dbase + 1][3], b4 = s_kn[dbase + 1][4], b5 = s_kn[dbase + 1][5],
          b6 = s_kn[dbase + 1][6];
    float c0 = s_kn[dbase + 2][0], c1 = s_kn[dbase + 2][1], c2 = s_kn[dbase + 2][2],
          c3 = s_kn[dbase + 2][3], c4 = s_kn[dbase + 2][4], c5 = s_kn[dbase + 2][5],
          c6 = s_kn[dbase + 2][6];
    float e0 = s_kn[dbase + 3][0], e1 = s_kn[dbase + 3][1], e2 = s_kn[dbase + 3][2],
          e3 = s_kn[dbase + 3][3], e4 = s_kn[dbase + 3][4], e5 = s_kn[dbase + 3][5],
          e6 = s_kn[dbase + 3][6];

    const float4* __restrict__ r0 = &s_T[dbase + 0][0];
    const float4* __restrict__ r1 = &s_T[dbase + 1][0];
    const float4* __restrict__ r2 = &s_T[dbase + 2][0];
    const float4* __restrict__ r3 = &s_T[dbase + 3][0];

    auto evalone = [&](float xx,
                       float k0, float k1, float k2, float k3, float k4, float k5, float k6,
                       const float4* __restrict__ row) -> float {
        // 3-level binary search (round 11)
        const bool  gt3 = xx >= k3;
        const float kA  = gt3 ? k5 : k1;
        const bool  gtA = xx >= kA;
        const float kB0 = gt3 ? k4 : k0;
        const float kB1 = gt3 ? k6 : k2;
        const float kB  = gtA ? kB1 : kB0;
        const bool  gtB = xx >= kB;
        int idx = (gtB ? 1 : 0) + (gtA ? 2 : 0) + (gt3 ? 4 : 0);

        const float4 T = row[idx ^ key];   // one ds_read_b128

        const __half2* hp = reinterpret_cast<const __half2*>(&T.z);
        const float2 f1 = __half22float2(hp[0]);   // {ch, h}
        const float2 f2 = __half22float2(hp[1]);   // {d0, d1}
        const float ch = f1.x, h = f1.y, d0 = f2.x, d1 = f2.y;

        const float theta = fmaf(xx, T.x, T.y);
        const float delta = h * T.x;                              // h*invw
        const float dmd   = delta - d0;
        const float s2    = fmaf(-2.0f, delta, d0 + d1);
        const float u     = fmaf(-theta, theta, theta);           // θ(1-θ)
        const float den   = fmaf(s2, u, delta);
        const float rden  = __builtin_amdgcn_rcpf(den);
        const float num1  = (h * theta) * fmaf(theta, dmd, d0);   // hθ(θ(δ-d0)+d0)
        const float zin   = fmaf(num1, rden, ch);
        const float poly  = fmaf(fmaf(s2, theta, dmd + dmd), theta, d0);
        const float ee    = delta * rden;
        const float lg2   = __log2f(poly * (ee * ee));

        const bool inside = fabsf(xx) <= TB;
        const float z    = inside ? zin : xx;
        const float lg2s = inside ? lg2 : 0.0f;
        return fmaf(z * z, -0.5f, fmaf(lg2s, LN2, -HALF_LOG_2PI));
    };

    auto eval4 = [&](f32x4 xv) -> f32x4 {
        f32x4 r;
        r.x = evalone(xv.x, a0, a1, a2, a3, a4, a5, a6, r0);
        r.y = evalone(xv.y, b0, b1, b2, b3, b4, b5, b6, r1);
        r.z = evalone(xv.z, c0, c1, c2, c3, c4, c5, c6, r2);
        r.w = evalone(xv.w, e0, e1, e2, e3, e4, e5, e6, r3);
        return r;
    };

    const f32x4* __restrict__ x4 = reinterpret_cast<const f32x4*>(x);
    f32x4* __restrict__ o4 = reinterpret_cast<f32x4*>(out);

    const int W  = g >> 6;            // global wave id
    const int nW = nT >> 6;           // total waves
    const int SUPER = nW << 8;        // quads per super-iteration (32MB sweep window)
    const int nS = (SUPER > 0) ? (n4 / SUPER) : 0;

    if (nS > 0 && (n4 % SUPER) == 0) {
        // ---- pipelined sweep: prologue loads, then {prefetch s+1 | compute s} ----
        int base = (W << 8) + l;
        f32x4 v0 = x4[base];
        f32x4 v1 = x4[base + 64];
        f32x4 v2 = x4[base + 128];
        f32x4 v3 = x4[base + 192];
        for (int s = 1; s < nS; ++s) {
            const int nbase = base + SUPER;
            const f32x4 p0 = x4[nbase];          // in flight across the whole
            const f32x4 p1 = x4[nbase + 64];     // compute+store block below
            const f32x4 p2 = x4[nbase + 128];
            const f32x4 p3 = x4[nbase + 192];
            __builtin_nontemporal_store(eval4(v0), &o4[base]);
            __builtin_nontemporal_store(eval4(v1), &o4[base + 64]);
            __builtin_nontemporal_store(eval4(v2), &o4[base + 128]);
            __builtin_nontemporal_store(eval4(v3), &o4[base + 192]);
            v0 = p0; v1 = p1; v2 = p2; v3 = p3;
            base = nbase;
        }
        __builtin_nontemporal_store(eval4(v0), &o4[base]);
        __builtin_nontemporal_store(eval4(v1), &o4[base + 64]);
        __builtin_nontemporal_store(eval4(v2), &o4[base + 128]);
        __builtin_nontemporal_store(eval4(v3), &o4[base + 192]);
    } else {
        // general fallback (not hit at N=1048576, D=32)
        for (int i = g; i < n4; i += nT) {
            const f32x4 xa = x4[i];
            __builtin_nontemporal_store(eval4(xa), &o4[i]);
        }
    }
}

extern "C" void kernel_launch(void* const* d_in, const int* in_sizes, int n_in,
                              void* d_out, int out_size, void* d_ws, size_t ws_size,
                              hipStream_t stream) {
    const float* x  = (const float*)d_in[0];
    const float* uw = (const float*)d_in[1];
    const float* uh = (const float*)d_in[2];
    const float* ud = (const float*)d_in[3];
    float* out = (float*)d_out;

    const int n4 = in_sizes[0] / 4;                 // N*D/4 float4 elements
    int blocks = (n4 + 255) / 256;
    if (blocks > 2048) blocks = 2048;

    mfb_kernel<<<blocks, 256, 0, stream>>>(x, uw, uh, ud, out, n4);
}

// Round 15
// 51.976 us; speedup vs baseline: 1.0702x; 1.0330x over previous
//
#include <hip/hip_runtime.h>
#include <hip/hip_fp16.h>
#include <math.h>

#define NB 8          // NUM_BINS
#define DD 32         // D
constexpr float TB   = 10.0f;   // TAIL_BOUND
constexpr float MBW  = 1e-3f;   // MIN_BIN_WIDTH
constexpr float MBH  = 1e-3f;   // MIN_BIN_HEIGHT
constexpr float MDER = 1e-3f;   // MIN_DERIVATIVE

typedef float f32x4 __attribute__((ext_vector_type(4)));

__device__ __forceinline__ float softplusf(float v) {
    return (v > 20.0f) ? v : log1pf(expf(v));
}

__global__ __launch_bounds__(256, 4) void mfb_kernel(
    const float* __restrict__ x,
    const float* __restrict__ uw,
    const float* __restrict__ uh,
    const float* __restrict__ ud,
    float* __restrict__ out,
    int n4)
{
    // Round-12 structure (best: 52.5us). Single variable: wave burst length
    // within the coherent sweep, 4KB -> 8KB. Each wave owns 8 consecutive
    // 1KB lines per super-iteration (two R12 bodies back-to-back); consecutive
    // waves stay adjacent so the grid sweeps a contiguous 64MB window (R13
    // proved private blocks lose the sweep coherence and regress). No
    // pipeline (R14: flat, cost occupancy). VGPR stays ~44.
    __shared__ float4 s_T[DD][NB + 1];
    __shared__ float  s_kn[DD][7];

    const int t = threadIdx.x;

    if (t < DD) {
        float posw[NB + 1], posh[NB + 1], dv[NB + 1];
        // ---- widths ----
        {
            float u[NB];
            float m = -1e30f;
            #pragma unroll
            for (int k = 0; k < NB; ++k) { u[k] = uw[t * NB + k]; m = fmaxf(m, u[k]); }
            float s = 0.0f;
            #pragma unroll
            for (int k = 0; k < NB; ++k) { u[k] = expf(u[k] - m); s += u[k]; }
            const float inv = 1.0f / s;
            posw[0] = -TB;
            float cum = 0.0f;
            #pragma unroll
            for (int k = 0; k < NB; ++k) {
                cum += MBW + (1.0f - MBW * (float)NB) * (u[k] * inv);
                posw[k + 1] = 2.0f * TB * cum - TB;
            }
            posw[NB] = TB;
        }
        // ---- heights ----
        {
            float u[NB];
            float m = -1e30f;
            #pragma unroll
            for (int k = 0; k < NB; ++k) { u[k] = uh[t * NB + k]; m = fmaxf(m, u[k]); }
            float s = 0.0f;
            #pragma unroll
            for (int k = 0; k < NB; ++k) { u[k] = expf(u[k] - m); s += u[k]; }
            const float inv = 1.0f / s;
            posh[0] = -TB;
            float cum = 0.0f;
            #pragma unroll
            for (int k = 0; k < NB; ++k) {
                cum += MBH + (1.0f - MBH * (float)NB) * (u[k] * inv);
                posh[k + 1] = 2.0f * TB * cum - TB;
            }
            posh[NB] = TB;
        }
        // ---- derivatives ----
        {
            const float c   = logf(expm1f(1.0f - MDER));
            const float bnd = MDER + softplusf(c);   // == 1.0 to fp precision
            dv[0]  = bnd;
            dv[NB] = bnd;
            #pragma unroll
            for (int k = 1; k < NB; ++k)
                dv[k] = MDER + softplusf(ud[t * (NB - 1) + (k - 1)]);
        }
        // ---- publish ----
        #pragma unroll
        for (int k = 0; k < 7; ++k) s_kn[t][k] = posw[k + 1];
        const int key = (t >> 2) & 7;
        #pragma unroll
        for (int b = 0; b < NB; ++b) {
            const float w    = posw[b + 1] - posw[b];
            const float invw = 1.0f / w;
            const unsigned u1 = ((unsigned)__half_as_ushort(__float2half_rn(posh[b + 1] - posh[b])) << 16)
                              |  (unsigned)__half_as_ushort(__float2half_rn(posh[b]));
            const unsigned u2 = ((unsigned)__half_as_ushort(__float2half_rn(dv[b + 1])) << 16)
                              |  (unsigned)__half_as_ushort(__float2half_rn(dv[b]));
            float4 T;
            T.x = invw;
            T.y = -posw[b] * invw;
            T.z = __uint_as_float(u1);
            T.w = __uint_as_float(u2);
            s_T[t][b ^ key] = T;
        }
    }
    __syncthreads();

    constexpr float HALF_LOG_2PI = 0.91893853320467274178f;
    constexpr float LN2          = 0.69314718055994530942f;

    const int g      = blockIdx.x * blockDim.x + t;
    const int nT     = gridDim.x * blockDim.x;
    const int l      = g & 63;                 // lane
    // all burst offsets are 0 mod 32 -> dim quad = 4*(l&7), fixed per thread
    const int dbase  = (l * 4) & (DD - 1);
    const int key    = (dbase >> 2) & 7;

    float a0 = s_kn[dbase + 0][0], a1 = s_kn[dbase + 0][1], a2 = s_kn[dbase + 0][2],
          a3 = s_kn[dbase + 0][3], a4 = s_kn[dbase + 0][4], a5 = s_kn[dbase + 0][5],
          a6 = s_kn[dbase + 0][6];
    float b0 = s_kn[dbase + 1][0], b1 = s_kn[dbase + 1][1], b2 = s_kn[dbase + 1][2],
          b3 = s_kn[dbase + 1][3], b4 = s_kn[dbase + 1][4], b5 = s_kn[dbase + 1][5],
          b6 = s_kn[dbase + 1][6];
    float c0 = s_kn[dbase + 2][0], c1 = s_kn[dbase + 2][1], c2 = s_kn[dbase + 2][2],
          c3 = s_kn[dbase + 2][3], c4 = s_kn[dbase + 2][4], c5 = s_kn[dbase + 2][5],
          c6 = s_kn[dbase + 2][6];
    float e0 = s_kn[dbase + 3][0], e1 = s_kn[dbase + 3][1], e2 = s_kn[dbase + 3][2],
          e3 = s_kn[dbase + 3][3], e4 = s_kn[dbase + 3][4], e5 = s_kn[dbase + 3][5],
          e6 = s_kn[dbase + 3][6];

    const float4* __restrict__ r0 = &s_T[dbase + 0][0];
    const float4* __restrict__ r1 = &s_T[dbase + 1][0];
    const float4* __restrict__ r2 = &s_T[dbase + 2][0];
    const float4* __restrict__ r3 = &s_T[dbase + 3][0];

    auto evalone = [&](float xx,
                       float k0, float k1, float k2, float k3, float k4, float k5, float k6,
                       const float4* __restrict__ row) -> float {
        // 3-level binary search (round 11)
        const bool  gt3 = xx >= k3;
        const float kA  = gt3 ? k5 : k1;
        const bool  gtA = xx >= kA;
        const float kB0 = gt3 ? k4 : k0;
        const float kB1 = gt3 ? k6 : k2;
        const float kB  = gtA ? kB1 : kB0;
        const bool  gtB = xx >= kB;
        int idx = (gtB ? 1 : 0) + (gtA ? 2 : 0) + (gt3 ? 4 : 0);

        const float4 T = row[idx ^ key];   // one ds_read_b128

        const __half2* hp = reinterpret_cast<const __half2*>(&T.z);
        const float2 f1 = __half22float2(hp[0]);   // {ch, h}
        const float2 f2 = __half22float2(hp[1]);   // {d0, d1}
        const float ch = f1.x, h = f1.y, d0 = f2.x, d1 = f2.y;

        const float theta = fmaf(xx, T.x, T.y);
        const float delta = h * T.x;                              // h*invw
        const float dmd   = delta - d0;
        const float s2    = fmaf(-2.0f, delta, d0 + d1);
        const float u     = fmaf(-theta, theta, theta);           // θ(1-θ)
        const float den   = fmaf(s2, u, delta);
        const float rden  = __builtin_amdgcn_rcpf(den);
        const float num1  = (h * theta) * fmaf(theta, dmd, d0);   // hθ(θ(δ-d0)+d0)
        const float zin   = fmaf(num1, rden, ch);
        const float poly  = fmaf(fmaf(s2, theta, dmd + dmd), theta, d0);
        const float ee    = delta * rden;
        const float lg2   = __log2f(poly * (ee * ee));

        const bool inside = fabsf(xx) <= TB;
        const float z    = inside ? zin : xx;
        const float lg2s = inside ? lg2 : 0.0f;
        return fmaf(z * z, -0.5f, fmaf(lg2s, LN2, -HALF_LOG_2PI));
    };

    auto eval4 = [&](f32x4 xv) -> f32x4 {
        f32x4 r;
        r.x = evalone(xv.x, a0, a1, a2, a3, a4, a5, a6, r0);
        r.y = evalone(xv.y, b0, b1, b2, b3, b4, b5, b6, r1);
        r.z = evalone(xv.z, c0, c1, c2, c3, c4, c5, c6, r2);
        r.w = evalone(xv.w, e0, e1, e2, e3, e4, e5, e6, r3);
        return r;
    };

    const f32x4* __restrict__ x4 = reinterpret_cast<const f32x4*>(x);
    f32x4* __restrict__ o4 = reinterpret_cast<f32x4*>(out);

    const int W  = g >> 6;            // global wave id
    const int nW = nT >> 6;           // total waves
    const int SUPER = nW << 9;        // quads per super-iteration (8 lines/wave)
    const int nS = (SUPER > 0) ? (n4 / SUPER) : 0;

    if (nS > 0 && (n4 % SUPER) == 0) {
        for (int s = 0; s < nS; ++s) {
            const int base = s * SUPER + (W << 9) + l;
            #pragma unroll
            for (int j = 0; j < 2; ++j) {
                const int b = base + (j << 8);
                // 4 consecutive 1KB lines; j=0,1 back-to-back -> 8KB/wave burst
                const f32x4 v0 = x4[b];
                const f32x4 v1 = x4[b + 64];
                const f32x4 v2 = x4[b + 128];
                const f32x4 v3 = x4[b + 192];
                __builtin_nontemporal_store(eval4(v0), &o4[b]);
                __builtin_nontemporal_store(eval4(v1), &o4[b + 64]);
                __builtin_nontemporal_store(eval4(v2), &o4[b + 128]);
                __builtin_nontemporal_store(eval4(v3), &o4[b + 192]);
            }
        }
    } else {
        // general fallback (not hit at N=1048576, D=32)
        for (int i = g; i < n4; i += nT) {
            const f32x4 xa = x4[i];
            __builtin_nontemporal_store(eval4(xa), &o4[i]);
        }
    }
}

extern "C" void kernel_launch(void* const* d_in, const int* in_sizes, int n_in,
                              void* d_out, int out_size, void* d_ws, size_t ws_size,
                              hipStream_t stream) {
    const float* x  = (const float*)d_in[0];
    const float* uw = (const float*)d_in[1];
    const float* uh = (const float*)d_in[2];
    const float* ud = (const float*)d_in[3];
    float* out = (float*)d_out;

    const int n4 = in_sizes[0] / 4;                 // N*D/4 float4 elements
    int blocks = (n4 + 255) / 256;
    if (blocks > 2048) blocks = 2048;

    mfb_kernel<<<blocks, 256, 0, stream>>>(x, uw, uh, ud, out, n4);
}